// Round 4
// baseline (105.299 us; speedup 1.0000x reference)
//
#include <hip/hip_runtime.h>
#include <hip/hip_bf16.h>

#define BB 8
#define CC 128
#define NN 4096
#define KCQ 32

typedef unsigned short u16;
typedef unsigned int u32;
typedef unsigned char u8;
typedef __bf16 bf16x8 __attribute__((ext_vector_type(8)));
typedef float f32x4 __attribute__((ext_vector_type(4)));
typedef long i64;

typedef const __attribute__((address_space(1))) void gas_t;
typedef __attribute__((address_space(3))) void las_t;

__device__ __forceinline__ u16 f2bf(float f){
  u32 u = __builtin_bit_cast(u32, f);
  u32 r = u + 0x7FFFu + ((u >> 16) & 1u);
  return (u16)(r >> 16);
}
__device__ __forceinline__ u32 cvtpk(float lo, float hi){
  u32 r; asm("v_cvt_pk_bf16_f32 %0, %1, %2" : "=v"(r) : "v"(lo), "v"(hi)); return r;
}
__device__ __forceinline__ u32 pk_fp8x4(float a, float b, float c, float d){
  int v = 0;
  v = __builtin_amdgcn_cvt_pk_fp8_f32(a, b, v, false);
  v = __builtin_amdgcn_cvt_pk_fp8_f32(c, d, v, true);
  return (u32)v;
}
__device__ __forceinline__ void gload16(const void* g, void* l){
  __builtin_amdgcn_global_load_lds((gas_t*)g, (las_t*)l, 16, 0, 0);
}

// ---- kernel 0: weights f32 -> bf16 (Wq folds 1/sqrt(32)*log2(e) for exp2 softmax)
__global__ __launch_bounds__(256) void k_prep_w(const float* Wq, const float* Wk,
                                                const float* Wv, const float* Wo,
                                                u16* wsq, u16* wsk, u16* wsv, u16* wso){
  int i = blockIdx.x * 256 + threadIdx.x;
  const float SC = 0.2550350f; // log2(e)/sqrt(32)
  if (i < 4096)       wsq[i]        = f2bf(Wq[i] * SC);
  else if (i < 8192)  wsk[i-4096]   = f2bf(Wk[i-4096]);
  else if (i < 24576) wsv[i-8192]   = f2bf(Wv[i-8192]);
  else if (i < 40960) wso[i-24576]  = f2bf(Wo[i-24576]);
}

// ---- kernel 1: fused transpose+projection. 512 blocks x 256 thr; block = (b, 64-n tile).
// Stage x -> LDS [64n][132c] bf16, then 4 waves project 16 n each.
// Q,K bf16 [B][N][32]; V fp8 e4m3 [B][C][N] (mfma(x,Wv) -> 4 consecutive n pack per dword).
__global__ __launch_bounds__(256) void k_projx(const float* x, const u16* wq, const u16* wk,
                                               const u16* wv, u16* Qm, u16* Km, u8* Vt8){
  __shared__ u16 xL[64*132];
  int b = blockIdx.x >> 6, nb = (blockIdx.x & 63) * 64;
  int t = threadIdx.x;
  int n = t & 63, cg = t >> 6;
  #pragma unroll
  for (int it = 0; it < 32; ++it){
    int c = it*4 + cg;
    xL[n*132 + c] = f2bf(x[((size_t)b*CC + c)*NN + nb + n]);
  }
  __syncthreads();
  int w = t >> 6, l = t & 63, a = l & 15, g = l >> 4;
  int n0 = nb + w*16;
  bf16x8 xa[4];
  #pragma unroll
  for (int kc = 0; kc < 4; ++kc)
    xa[kc] = *(const bf16x8*)(xL + (w*16 + a)*132 + kc*32 + g*8);

  #pragma unroll
  for (int qt = 0; qt < 2; ++qt){
    f32x4 accq = {0.f,0.f,0.f,0.f}, acck = {0.f,0.f,0.f,0.f};
    #pragma unroll
    for (int kc = 0; kc < 4; ++kc){
      bf16x8 wbq = ((const bf16x8*)(wq + (size_t)(qt*16 + a) * CC))[kc*4 + g];
      bf16x8 wbk = ((const bf16x8*)(wk + (size_t)(qt*16 + a) * CC))[kc*4 + g];
      accq = __builtin_amdgcn_mfma_f32_16x16x32_bf16(xa[kc], wbq, accq, 0,0,0);
      acck = __builtin_amdgcn_mfma_f32_16x16x32_bf16(xa[kc], wbk, acck, 0,0,0);
    }
    #pragma unroll
    for (int r = 0; r < 4; ++r){
      Qm[((size_t)b*NN + n0 + 4*g + r) * KCQ + qt*16 + a] = f2bf(accq[r]);
      Km[((size_t)b*NN + n0 + 4*g + r) * KCQ + qt*16 + a] = f2bf(acck[r]);
    }
  }
  #pragma unroll
  for (int vt = 0; vt < 8; ++vt){
    f32x4 acc = {0.f,0.f,0.f,0.f};
    #pragma unroll
    for (int kc = 0; kc < 4; ++kc){
      bf16x8 wa = ((const bf16x8*)(wv + (size_t)(vt*16 + a) * CC))[kc*4 + g];
      acc = __builtin_amdgcn_mfma_f32_16x16x32_bf16(xa[kc], wa, acc, 0,0,0);
    }
    // D[row=n0+4g+r][col=vchan vt*16+a]: 4 consecutive n -> one fp8x4 dword
    *(u32*)(Vt8 + ((size_t)b*CC + vt*16 + a)*NN + n0 + 4*g) =
        pk_fp8x4(acc[0], acc[1], acc[2], acc[3]);
  }
}

// ---- kernel 2: flash attention; m=0 (bounded scores), fp8 PV, key-sliced QK.
// 8 waves: halves h=0/1 cover keys [0,2048)/[2048,4096) for the same 64 queries.
// Per half: wave wq owns keys wq*16..+16 in QK (Q all-64q in regs), vchans wq*32..+32 in PV.
// K bf16 + V fp8 double-buffered LDS via global_load_lds; counted vmcnt(3); 3 barriers/kt.
// P fp8 [64q][64k] per half, XOR swizzle byte^=(row&3)<<4 on 64B rows (also V rows).
__global__ __launch_bounds__(512, 4) void k_attn(const u16* Qm, const u16* Km,
                                                 const u8* Vt8, u16* Ow){
  __shared__ __align__(16) char smem[59392];
  // K: sb*8192 + h*4096            [64k][32c] bf16 (linear)
  // V: 16384 + sb*16384 + h*8192   [128v][64k] fp8 (row-XOR swizzled)
  // P: 49152 + h*4096              [64q][64k] fp8 (row-XOR swizzled)
  // Ml: 57344  [8 waves][64q] f32
  // Cx overlay (epilogue): [64q][132] f32 at offset 0
  int bid = blockIdx.x;
  int b = bid & 7, qb = bid >> 3;    // one batch per XCD
  int t = threadIdx.x;
  int l = t & 63, a = l & 15, g = l >> 4;
  int w = t >> 6, h = w >> 2, wq = w & 3;
  int q0 = qb * 64;
  int kb0 = h * 2048;

  const u16* Kb = Km + (size_t)b * NN * KCQ;
  const u8*  Vb = Vt8 + (size_t)b * CC * NN;

  // Q frags: all 64 queries (B-operand layout)
  bf16x8 qf[4];
  #pragma unroll
  for (int qs = 0; qs < 4; ++qs)
    qf[qs] = ((const bf16x8*)(Qm + ((size_t)b*NN + q0 + qs*16 + a) * KCQ))[g];

  f32x4 o[8];                        // [qs*2+st] = O^T[wq*32+st*16+4g+r][qs*16+a]
  #pragma unroll
  for (int i = 0; i < 8; ++i) o[i] = (f32x4){0.f,0.f,0.f,0.f};
  float ls[4] = {0.f, 0.f, 0.f, 0.f};

  // staging addresses (lane-linear LDS dests; V source pre-swizzled)
  const u16* kSrc = Kb + (size_t)(kb0 + wq*16 + (l>>2)) * KCQ + (l&3)*8;
  char* kD0 = smem + h*4096 + wq*1024 + l*16;
  char* kD1 = smem + 8192 + h*4096 + wq*1024 + l*16;
  int vrow = wq*32 + (l>>2);
  const u8* vSrc = Vb + (size_t)vrow*NN + kb0 + (((l&3) ^ ((l>>2)&3)) << 4);
  char* vD0 = smem + 16384 + h*8192 + wq*2048 + l*16;
  char* vD1 = smem + 32768 + h*8192 + wq*2048 + l*16;

  auto stage = [&](int kt1, int d1){
    gload16(kSrc + (size_t)kt1*64*KCQ, d1 ? kD1 : kD0);
    const u8* vs = vSrc + kt1*64;
    char* vd = d1 ? vD1 : vD0;
    gload16(vs, vd);
    gload16(vs + (size_t)16*NN, vd + 1024);
  };

  stage(0, 0);
  asm volatile("s_waitcnt vmcnt(0)" ::: "memory");
  __builtin_amdgcn_s_barrier();

  const int sx = (a & 3) << 4;
  char* Pw = smem + 49152 + h*4096;
  const char* Ph = Pw;

  int sb = 0;
  for (int kt = 0; kt < 32; ++kt){
    if (kt < 31){
      stage(kt+1, sb^1);
      asm volatile("s_waitcnt vmcnt(3)" ::: "memory");
    } else {
      asm volatile("s_waitcnt vmcnt(0)" ::: "memory");
    }
    __builtin_amdgcn_s_barrier();      // A: tile-kt K/V valid block-wide

    // QK: S^T[key wq*16+4g+r][q qs*16+a], A = K-frag (own 16-key slice)
    const char* Ks = smem + sb*8192 + h*4096;
    bf16x8 kf = *(const bf16x8*)(Ks + (wq*16 + a)*64 + g*16);
    f32x4 sv[4];
    #pragma unroll
    for (int qs = 0; qs < 4; ++qs){
      f32x4 z = {0.f,0.f,0.f,0.f};
      sv[qs] = __builtin_amdgcn_mfma_f32_16x16x32_bf16(kf, qf[qs], z, 0,0,0);
    }
    // softmax (m=0): p = exp2(s); fp8 pack, one dword per q-subtile
    #pragma unroll
    for (int qs = 0; qs < 4; ++qs){
      float p0 = __builtin_amdgcn_exp2f(sv[qs][0]);
      float p1 = __builtin_amdgcn_exp2f(sv[qs][1]);
      float p2 = __builtin_amdgcn_exp2f(sv[qs][2]);
      float p3 = __builtin_amdgcn_exp2f(sv[qs][3]);
      ls[qs] += (p0 + p1) + (p2 + p3);
      *(u32*)(Pw + (qs*16 + a)*64 + ((wq*16 + 4*g) ^ sx)) = pk_fp8x4(p0, p1, p2, p3);
    }
    asm volatile("s_waitcnt lgkmcnt(0)" ::: "memory");
    __builtin_amdgcn_s_barrier();      // B: P visible block-wide

    // PV (fp8): O^T[wq*32 slice][all 64 q]
    const char* Vs = smem + 16384 + sb*16384 + h*8192;
    __builtin_amdgcn_s_setprio(1);
    #pragma unroll
    for (int kk = 0; kk < 2; ++kk){
      int kx = (kk*32 + 8*g) ^ sx;
      i64 vf0 = *(const i64*)(Vs + (wq*32 + a)*64 + kx);
      i64 vf1 = *(const i64*)(Vs + (wq*32 + 16 + a)*64 + kx);
      i64 pf[4];
      #pragma unroll
      for (int qs = 0; qs < 4; ++qs)
        pf[qs] = *(const i64*)(Ph + (qs*16 + a)*64 + kx);
      #pragma unroll
      for (int qs = 0; qs < 4; ++qs){
        o[qs*2  ] = __builtin_amdgcn_mfma_f32_16x16x32_fp8_fp8(vf0, pf[qs], o[qs*2  ], 0,0,0);
        o[qs*2+1] = __builtin_amdgcn_mfma_f32_16x16x32_fp8_fp8(vf1, pf[qs], o[qs*2+1], 0,0,0);
      }
    }
    __builtin_amdgcn_s_setprio(0);
    __builtin_amdgcn_s_barrier();      // B2: PV reads done -> buffers reusable
    sb ^= 1;
  }

  // epilogue: l reduce (over g) + cross-wave sum; combine halves; write O bf16
  #pragma unroll
  for (int qs = 0; qs < 4; ++qs){
    ls[qs] += __shfl_xor(ls[qs], 16);
    ls[qs] += __shfl_xor(ls[qs], 32);
  }
  float* Ml = (float*)(smem + 57344);
  if (l < 16){
    #pragma unroll
    for (int qs = 0; qs < 4; ++qs) Ml[w*64 + qs*16 + l] = ls[qs];
  }
  float* Cx = (float*)smem;
  __syncthreads();
  if (h == 1){
    #pragma unroll
    for (int i = 0; i < 8; ++i){
      int qs = i >> 1, st = i & 1;
      *(f32x4*)(Cx + (qs*16 + a)*132 + wq*32 + st*16 + 4*g) = o[i];
    }
  }
  __syncthreads();
  if (h == 0){
    #pragma unroll
    for (int qs = 0; qs < 4; ++qs){
      float lsum = 0.f;
      #pragma unroll
      for (int ww = 0; ww < 8; ++ww) lsum += Ml[ww*64 + qs*16 + a];
      float inv = 1.f / lsum;
      #pragma unroll
      for (int st = 0; st < 2; ++st){
        f32x4 oc = o[qs*2 + st];
        const float* cx = Cx + (qs*16 + a)*132 + wq*32 + st*16 + 4*g;
        float v0 = (oc[0] + cx[0]) * inv;
        float v1 = (oc[1] + cx[1]) * inv;
        float v2 = (oc[2] + cx[2]) * inv;
        float v3 = (oc[3] + cx[3]) * inv;
        uint2 pk; pk.x = cvtpk(v0, v1); pk.y = cvtpk(v2, v3);
        *(uint2*)(Ow + ((size_t)b*NN + q0 + qs*16 + a)*CC + wq*32 + st*16 + 4*g) = pk;
      }
    }
  }
}

// ---- kernel 3: y = x + gamma * (O @ Wo^T), 1 wave/block, 16 n per wave
__global__ __launch_bounds__(64) void k_out(const u16* Ow, const u16* wo, const float* x,
                                            const float* gamma, float* out){
  int bid = blockIdx.x;
  int b = bid >> 8, nt = bid & 255;
  int nb = nt * 16;
  int l = threadIdx.x, a = l & 15, g = l >> 4;
  float gm = gamma[0];
  bf16x8 ob[4];
  #pragma unroll
  for (int kc = 0; kc < 4; ++kc)
    ob[kc] = ((const bf16x8*)(Ow + ((size_t)b*NN + nb + a) * CC))[kc*4 + g];
  #pragma unroll
  for (int ot = 0; ot < 8; ++ot){
    f32x4 acc = {0.f,0.f,0.f,0.f};
    #pragma unroll
    for (int kc = 0; kc < 4; ++kc){
      bf16x8 wf = ((const bf16x8*)(wo + (size_t)(ot*16 + a) * CC))[kc*4 + g];
      acc = __builtin_amdgcn_mfma_f32_16x16x32_bf16(wf, ob[kc], acc, 0,0,0);
    }
    #pragma unroll
    for (int r = 0; r < 4; ++r){
      size_t idx = ((size_t)b*CC + ot*16 + 4*g + r) * NN + nb + a;
      out[idx] = x[idx] + gm * acc[r];
    }
  }
}

extern "C" void kernel_launch(void* const* d_in, const int* in_sizes, int n_in,
                              void* d_out, int out_size, void* d_ws, size_t ws_size,
                              hipStream_t stream) {
  const float* x     = (const float*)d_in[0];
  const float* Wq    = (const float*)d_in[1];
  const float* Wk    = (const float*)d_in[2];
  const float* Wv    = (const float*)d_in[3];
  const float* Wo    = (const float*)d_in[4];
  const float* gamma = (const float*)d_in[5];
  float* out = (float*)d_out;

  u16* wsq = (u16*)d_ws;
  u16* wsk = wsq + 4096;
  u16* wsv = wsk + 4096;
  u16* wso = wsv + 16384;
  u16* Qm  = wso + 16384;
  u16* Km  = Qm + (size_t)BB*NN*KCQ;
  u8*  Vt8 = (u8*)(Km + (size_t)BB*NN*KCQ);
  u16* Ow  = (u16*)(Vt8 + (size_t)BB*CC*NN);

  hipLaunchKernelGGL(k_prep_w, dim3(160), dim3(256), 0, stream, Wq, Wk, Wv, Wo, wsq, wsk, wsv, wso);
  hipLaunchKernelGGL(k_projx,  dim3(512), dim3(256), 0, stream, x, wsq, wsk, wsv, Qm, Km, Vt8);
  hipLaunchKernelGGL(k_attn,   dim3(512), dim3(512), 0, stream, Qm, Km, Vt8, Ow);
  hipLaunchKernelGGL(k_out,    dim3(2048), dim3(64), 0, stream, Ow, wso, x, gamma, out);
}

// Round 6
// 93.178 us; speedup vs baseline: 1.1301x; 1.1301x over previous
//
#include <hip/hip_runtime.h>
#include <hip/hip_bf16.h>

#define BB 8
#define CC 128
#define NN 4096
#define KCQ 32

typedef unsigned short u16;
typedef unsigned int u32;
typedef unsigned char u8;
typedef __bf16 bf16x8 __attribute__((ext_vector_type(8)));
typedef float f32x4 __attribute__((ext_vector_type(4)));
typedef long i64;

typedef const __attribute__((address_space(1))) void gas_t;
typedef __attribute__((address_space(3))) void las_t;

__device__ __forceinline__ u16 f2bf(float f){
  u32 u = __builtin_bit_cast(u32, f);
  u32 r = u + 0x7FFFu + ((u >> 16) & 1u);
  return (u16)(r >> 16);
}
__device__ __forceinline__ u32 cvtpk(float lo, float hi){
  u32 r; asm("v_cvt_pk_bf16_f32 %0, %1, %2" : "=v"(r) : "v"(lo), "v"(hi)); return r;
}
__device__ __forceinline__ u32 pk_fp8x4(float a, float b, float c, float d){
  int v = 0;
  v = __builtin_amdgcn_cvt_pk_fp8_f32(a, b, v, false);
  v = __builtin_amdgcn_cvt_pk_fp8_f32(c, d, v, true);
  return (u32)v;
}
__device__ __forceinline__ void gload16(const void* g, void* l){
  __builtin_amdgcn_global_load_lds((gas_t*)g, (las_t*)l, 16, 0, 0);
}

// ---- kernel 0: weights f32 -> bf16 (Wq folds 1/sqrt(32)*log2(e) for exp2 softmax)
__global__ __launch_bounds__(256) void k_prep_w(const float* Wq, const float* Wk,
                                                const float* Wv, const float* Wo,
                                                u16* wsq, u16* wsk, u16* wsv, u16* wso){
  int i = blockIdx.x * 256 + threadIdx.x;
  const float SC = 0.2550350f; // log2(e)/sqrt(32)
  if (i < 4096)       wsq[i]        = f2bf(Wq[i] * SC);
  else if (i < 8192)  wsk[i-4096]   = f2bf(Wk[i-4096]);
  else if (i < 24576) wsv[i-8192]   = f2bf(Wv[i-8192]);
  else if (i < 40960) wso[i-24576]  = f2bf(Wo[i-24576]);
}

// ---- kernel 1: fused transpose+projection. 512 blocks x 256 thr; block = (b, 64-n tile).
__global__ __launch_bounds__(256) void k_projx(const float* x, const u16* wq, const u16* wk,
                                               const u16* wv, u16* Qm, u16* Km, u8* Vt8){
  __shared__ u16 xL[64*132];
  int b = blockIdx.x >> 6, nb = (blockIdx.x & 63) * 64;
  int t = threadIdx.x;
  int n = t & 63, cg = t >> 6;
  #pragma unroll
  for (int it = 0; it < 32; ++it){
    int c = it*4 + cg;
    xL[n*132 + c] = f2bf(x[((size_t)b*CC + c)*NN + nb + n]);
  }
  __syncthreads();
  int w = t >> 6, l = t & 63, a = l & 15, g = l >> 4;
  int n0 = nb + w*16;
  bf16x8 xa[4];
  #pragma unroll
  for (int kc = 0; kc < 4; ++kc)
    xa[kc] = *(const bf16x8*)(xL + (w*16 + a)*132 + kc*32 + g*8);

  #pragma unroll
  for (int qt = 0; qt < 2; ++qt){
    f32x4 accq = {0.f,0.f,0.f,0.f}, acck = {0.f,0.f,0.f,0.f};
    #pragma unroll
    for (int kc = 0; kc < 4; ++kc){
      bf16x8 wbq = ((const bf16x8*)(wq + (size_t)(qt*16 + a) * CC))[kc*4 + g];
      bf16x8 wbk = ((const bf16x8*)(wk + (size_t)(qt*16 + a) * CC))[kc*4 + g];
      accq = __builtin_amdgcn_mfma_f32_16x16x32_bf16(xa[kc], wbq, accq, 0,0,0);
      acck = __builtin_amdgcn_mfma_f32_16x16x32_bf16(xa[kc], wbk, acck, 0,0,0);
    }
    #pragma unroll
    for (int r = 0; r < 4; ++r){
      Qm[((size_t)b*NN + n0 + 4*g + r) * KCQ + qt*16 + a] = f2bf(accq[r]);
      Km[((size_t)b*NN + n0 + 4*g + r) * KCQ + qt*16 + a] = f2bf(acck[r]);
    }
  }
  #pragma unroll
  for (int vt = 0; vt < 8; ++vt){
    f32x4 acc = {0.f,0.f,0.f,0.f};
    #pragma unroll
    for (int kc = 0; kc < 4; ++kc){
      bf16x8 wa = ((const bf16x8*)(wv + (size_t)(vt*16 + a) * CC))[kc*4 + g];
      acc = __builtin_amdgcn_mfma_f32_16x16x32_bf16(xa[kc], wa, acc, 0,0,0);
    }
    *(u32*)(Vt8 + ((size_t)b*CC + vt*16 + a)*NN + n0 + 4*g) =
        pk_fp8x4(acc[0], acc[1], acc[2], acc[3]);
  }
}

// ---- kernel 2: flash attention; m=0 (bounded scores), fp8 PV, key-sliced QK.
// All 64B LDS rows (K bf16, V fp8, P fp8) XOR-swizzled with key ((row>>1)&3)<<4:
// same-parity rows get distinct 16B slots -> worst 2-way (free). K/V staged via
// global_load_lds with pre-swizzled SOURCE chunks (linear lane-order dest, rule 21).
// 2 barriers/kt with counted vmcnt: B waits V[kt] (vmcnt(3)), B2 waits K[kt+1] (vmcnt(2));
// V[kt+1] stays in flight across B2, landing during next QK phase.
__global__ __launch_bounds__(512, 4) void k_attn(const u16* Qm, const u16* Km,
                                                 const u8* Vt8, u16* Ow){
  __shared__ __align__(16) char smem[59392];
  // K: sb*8192 + h*4096            [64k][32c] bf16, swizzled
  // V: 16384 + sb*16384 + h*8192   [128v][64k] fp8, swizzled
  // P: 49152 + h*4096              [64q][64k] fp8, swizzled
  // Ml: 57344  [8 waves][64q] f32
  // Cx overlay (epilogue): [64q][132] f32 at offset 0
  int bid = blockIdx.x;
  int b = bid & 7, qb = bid >> 3;    // one batch per XCD
  int t = threadIdx.x;
  int l = t & 63, a = l & 15, g = l >> 4;
  int w = t >> 6, h = w >> 2, wq = w & 3;
  int q0 = qb * 64;
  int kb0 = h * 2048;

  const u16* Kb = Km + (size_t)b * NN * KCQ;
  const u8*  Vb = Vt8 + (size_t)b * CC * NN;

  // Q frags: all 64 queries (B-operand layout)
  bf16x8 qf[4];
  #pragma unroll
  for (int qs = 0; qs < 4; ++qs)
    qf[qs] = ((const bf16x8*)(Qm + ((size_t)b*NN + q0 + qs*16 + a) * KCQ))[g];

  f32x4 o[8];                        // [qs*2+st] = O^T[wq*32+st*16+4g+r][qs*16+a]
  #pragma unroll
  for (int i = 0; i < 8; ++i) o[i] = (f32x4){0.f,0.f,0.f,0.f};
  float ls[4] = {0.f, 0.f, 0.f, 0.f};

  // staging: lane l owns row (l>>2), 16B chunk (l&3); source chunk pre-swizzled
  // by key ((row>>1)&3) = (l>>3)&3 so a linear LDS dest yields swizzled layout.
  int schk = (l&3) ^ ((l>>3)&3);
  const u16* kSrc = Kb + (size_t)(kb0 + wq*16 + (l>>2)) * KCQ + schk*8;
  char* kD0 = smem + h*4096 + wq*1024 + l*16;
  char* kD1 = smem + 8192 + h*4096 + wq*1024 + l*16;
  int vrow = wq*32 + (l>>2);
  const u8* vSrc = Vb + (size_t)vrow*NN + kb0 + (schk << 4);
  char* vD0 = smem + 16384 + h*8192 + wq*2048 + l*16;
  char* vD1 = smem + 32768 + h*8192 + wq*2048 + l*16;

  auto stage = [&](int kt1, int d1){
    gload16(kSrc + (size_t)kt1*64*KCQ, d1 ? kD1 : kD0);   // K first (waited at B2)
    const u8* vs = vSrc + kt1*64;
    char* vd = d1 ? vD1 : vD0;
    gload16(vs, vd);
    gload16(vs + (size_t)16*NN, vd + 1024);
  };

  stage(0, 0);
  asm volatile("s_waitcnt vmcnt(2)" ::: "memory");   // K(0) landed; V(0) in flight
  __builtin_amdgcn_s_barrier();

  const int cswz = (a >> 1) & 3;                     // row-derived XOR key for all reads
  char* Pw = smem + 49152 + h*4096;
  const char* Ph = Pw;

  int sb = 0;
  for (int kt = 0; kt < 32; ++kt){
    if (kt < 31) stage(kt+1, sb^1);

    // QK: S^T[key wq*16+4g+r][q qs*16+a], A = K-frag (own 16-key slice, self-staged)
    const char* Ks = smem + sb*8192 + h*4096;
    bf16x8 kf = *(const bf16x8*)(Ks + (wq*16 + a)*64 + ((g ^ cswz) << 4));
    f32x4 sv[4];
    #pragma unroll
    for (int qs = 0; qs < 4; ++qs){
      f32x4 z = {0.f,0.f,0.f,0.f};
      sv[qs] = __builtin_amdgcn_mfma_f32_16x16x32_bf16(kf, qf[qs], z, 0,0,0);
    }
    // softmax (m=0): p = exp2(s); fp8 pack, one dword per q-subtile
    #pragma unroll
    for (int qs = 0; qs < 4; ++qs){
      float p0 = __builtin_amdgcn_exp2f(sv[qs][0]);
      float p1 = __builtin_amdgcn_exp2f(sv[qs][1]);
      float p2 = __builtin_amdgcn_exp2f(sv[qs][2]);
      float p3 = __builtin_amdgcn_exp2f(sv[qs][3]);
      ls[qs] += (p0 + p1) + (p2 + p3);
      *(u32*)(Pw + (qs*16 + a)*64 + ((wq ^ cswz) << 4) + 4*g) = pk_fp8x4(p0, p1, p2, p3);
    }
    // B: V[kt] landed (vmcnt(3): K/V[kt+1] stay in flight), P visible block-wide
    if (kt < 31) { asm volatile("s_waitcnt vmcnt(3) lgkmcnt(0)" ::: "memory"); }
    else         { asm volatile("s_waitcnt vmcnt(0) lgkmcnt(0)" ::: "memory"); }
    __builtin_amdgcn_s_barrier();

    // PV (fp8): O^T[wq*32 slice][all 64 q]
    const char* Vs = smem + 16384 + sb*16384 + h*8192;
    __builtin_amdgcn_s_setprio(1);
    #pragma unroll
    for (int kk = 0; kk < 2; ++kk){
      int kx = (((kk*2 + (g>>1)) ^ cswz) << 4) + (g&1)*8;
      i64 vf0 = *(const i64*)(Vs + (wq*32 + a)*64 + kx);
      i64 vf1 = *(const i64*)(Vs + (wq*32 + 16 + a)*64 + kx);
      i64 pf[4];
      #pragma unroll
      for (int qs = 0; qs < 4; ++qs)
        pf[qs] = *(const i64*)(Ph + (qs*16 + a)*64 + kx);
      #pragma unroll
      for (int qs = 0; qs < 4; ++qs){
        o[qs*2  ] = __builtin_amdgcn_mfma_f32_16x16x32_fp8_fp8(vf0, pf[qs], o[qs*2  ], 0,0,0);
        o[qs*2+1] = __builtin_amdgcn_mfma_f32_16x16x32_fp8_fp8(vf1, pf[qs], o[qs*2+1], 0,0,0);
      }
    }
    __builtin_amdgcn_s_setprio(0);
    // B2: K[kt+1] landed (vmcnt(2): V[kt+1] stays in flight); PV reads done
    if (kt < 31) { asm volatile("s_waitcnt vmcnt(2)" ::: "memory"); }
    __builtin_amdgcn_s_barrier();
    sb ^= 1;
  }

  // epilogue: l reduce (over g) + cross-wave sum; combine halves; write O bf16
  #pragma unroll
  for (int qs = 0; qs < 4; ++qs){
    ls[qs] += __shfl_xor(ls[qs], 16);
    ls[qs] += __shfl_xor(ls[qs], 32);
  }
  float* Ml = (float*)(smem + 57344);
  if (l < 16){
    #pragma unroll
    for (int qs = 0; qs < 4; ++qs) Ml[w*64 + qs*16 + l] = ls[qs];
  }
  float* Cx = (float*)smem;
  __syncthreads();
  if (h == 1){
    #pragma unroll
    for (int i = 0; i < 8; ++i){
      int qs = i >> 1, st = i & 1;
      *(f32x4*)(Cx + (qs*16 + a)*132 + wq*32 + st*16 + 4*g) = o[i];
    }
  }
  __syncthreads();
  if (h == 0){
    #pragma unroll
    for (int qs = 0; qs < 4; ++qs){
      float lsum = 0.f;
      #pragma unroll
      for (int ww = 0; ww < 8; ++ww) lsum += Ml[ww*64 + qs*16 + a];
      float inv = 1.f / lsum;
      #pragma unroll
      for (int st = 0; st < 2; ++st){
        f32x4 oc = o[qs*2 + st];
        const float* cx = Cx + (qs*16 + a)*132 + wq*32 + st*16 + 4*g;
        float v0 = (oc[0] + cx[0]) * inv;
        float v1 = (oc[1] + cx[1]) * inv;
        float v2 = (oc[2] + cx[2]) * inv;
        float v3 = (oc[3] + cx[3]) * inv;
        uint2 pk; pk.x = cvtpk(v0, v1); pk.y = cvtpk(v2, v3);
        *(uint2*)(Ow + ((size_t)b*NN + q0 + qs*16 + a)*CC + wq*32 + st*16 + 4*g) = pk;
      }
    }
  }
}

// ---- kernel 3: y = x + gamma * (O @ Wo^T), 1 wave/block, 16 n per wave
__global__ __launch_bounds__(64) void k_out(const u16* Ow, const u16* wo, const float* x,
                                            const float* gamma, float* out){
  int bid = blockIdx.x;
  int b = bid >> 8, nt = bid & 255;
  int nb = nt * 16;
  int l = threadIdx.x, a = l & 15, g = l >> 4;
  float gm = gamma[0];
  bf16x8 ob[4];
  #pragma unroll
  for (int kc = 0; kc < 4; ++kc)
    ob[kc] = ((const bf16x8*)(Ow + ((size_t)b*NN + nb + a) * CC))[kc*4 + g];
  #pragma unroll
  for (int ot = 0; ot < 8; ++ot){
    f32x4 acc = {0.f,0.f,0.f,0.f};
    #pragma unroll
    for (int kc = 0; kc < 4; ++kc){
      bf16x8 wf = ((const bf16x8*)(wo + (size_t)(ot*16 + a) * CC))[kc*4 + g];
      acc = __builtin_amdgcn_mfma_f32_16x16x32_bf16(wf, ob[kc], acc, 0,0,0);
    }
    #pragma unroll
    for (int r = 0; r < 4; ++r){
      size_t idx = ((size_t)b*CC + ot*16 + 4*g + r) * NN + nb + a;
      out[idx] = x[idx] + gm * acc[r];
    }
  }
}

extern "C" void kernel_launch(void* const* d_in, const int* in_sizes, int n_in,
                              void* d_out, int out_size, void* d_ws, size_t ws_size,
                              hipStream_t stream) {
  const float* x     = (const float*)d_in[0];
  const float* Wq    = (const float*)d_in[1];
  const float* Wk    = (const float*)d_in[2];
  const float* Wv    = (const float*)d_in[3];
  const float* Wo    = (const float*)d_in[4];
  const float* gamma = (const float*)d_in[5];
  float* out = (float*)d_out;

  u16* wsq = (u16*)d_ws;
  u16* wsk = wsq + 4096;
  u16* wsv = wsk + 4096;
  u16* wso = wsv + 16384;
  u16* Qm  = wso + 16384;
  u16* Km  = Qm + (size_t)BB*NN*KCQ;
  u8*  Vt8 = (u8*)(Km + (size_t)BB*NN*KCQ);
  u16* Ow  = (u16*)(Vt8 + (size_t)BB*CC*NN);

  hipLaunchKernelGGL(k_prep_w, dim3(160), dim3(256), 0, stream, Wq, Wk, Wv, Wo, wsq, wsk, wsv, wso);
  hipLaunchKernelGGL(k_projx,  dim3(512), dim3(256), 0, stream, x, wsq, wsk, wsv, Qm, Km, Vt8);
  hipLaunchKernelGGL(k_attn,   dim3(512), dim3(512), 0, stream, Qm, Km, Vt8, Ow);
  hipLaunchKernelGGL(k_out,    dim3(2048), dim3(64), 0, stream, Ow, wso, x, gamma, out);
}